// Round 1
// baseline (2002.266 us; speedup 1.0000x reference)
//
#include <hip/hip_runtime.h>
#include <math.h>

// Problem constants (fixed by the reference)
#define B_  8
#define C_  256
#define N_  4096        // H*W = 64*64
#define CQK 32          // C/8
#define DSTACK 320      // 32(q) + 32(k) + 256(v)
#define SPLD 260        // padded row length for score/prob LDS tile

// ---------------------------------------------------------------------------
// Kernel 1: fused qkv projection.  qkv[b][dg][n], dg: 0..31 q, 32..63 k, 64..319 v
// grid (N/256, 320/32, B), 256 threads
// ---------------------------------------------------------------------------
__global__ __launch_bounds__(256) void proj_kernel(
    const float* __restrict__ x,
    const float* __restrict__ wq, const float* __restrict__ bq,
    const float* __restrict__ wk, const float* __restrict__ bk,
    const float* __restrict__ wv, const float* __restrict__ bv,
    float* __restrict__ qkv)
{
    __shared__ float w_s[32 * 256];
    const int tid = threadIdx.x;
    const int nb  = blockIdx.x;   // 0..15
    const int dt  = blockIdx.y;   // 0..9
    const int b   = blockIdx.z;   // 0..7
    const int dg0 = dt * 32;

    const float* wsrc;
    int row0;
    if (dt == 0)      { wsrc = wq; row0 = 0; }
    else if (dt == 1) { wsrc = wk; row0 = 0; }
    else              { wsrc = wv; row0 = dg0 - 64; }

    for (int idx = tid; idx < 32 * 256; idx += 256)
        w_s[idx] = wsrc[row0 * 256 + idx];
    __syncthreads();

    const int n = nb * 256 + tid;
    const float* xp = x + (size_t)b * C_ * N_ + n;

    float acc[32];
#pragma unroll
    for (int d = 0; d < 32; ++d) acc[d] = 0.f;

    for (int c4 = 0; c4 < C_; c4 += 4) {
        const float x0 = xp[(size_t)(c4 + 0) * N_];
        const float x1 = xp[(size_t)(c4 + 1) * N_];
        const float x2 = xp[(size_t)(c4 + 2) * N_];
        const float x3 = xp[(size_t)(c4 + 3) * N_];
#pragma unroll
        for (int d = 0; d < 32; ++d) {
            const float4 w = *(const float4*)&w_s[d * 256 + c4];
            acc[d] += w.x * x0 + w.y * x1 + w.z * x2 + w.w * x3;
        }
    }

#pragma unroll
    for (int d = 0; d < 32; ++d) {
        const int dg = dg0 + d;
        const float bb = (dg < 32) ? bq[dg] : (dg < 64 ? bk[dg - 32] : bv[dg - 64]);
        qkv[(size_t)b * DSTACK * N_ + (size_t)dg * N_ + n] = acc[d] + bb;
    }
}

// ---------------------------------------------------------------------------
// Kernel 2: flash-style attention + residual epilogue.
// block = 256 threads handles (b, 32-row i-tile); thread owns channel c = tid
// for PV phase.  grid (N/32, B).
// ---------------------------------------------------------------------------
__global__ __launch_bounds__(256, 4) void attn_kernel(
    const float* __restrict__ qkv,
    const float* __restrict__ x,
    const float* __restrict__ alpha_p,
    float* __restrict__ out)
{
    __shared__ float q_s[32 * 32];          // q tile [i][d]
    __shared__ float sp[32 * SPLD];         // scores -> probs [i][j] (padded)
    __shared__ float m_s[32], l_s[32], a_s[32];

    const int tid = threadIdx.x;
    const int it  = blockIdx.x;             // i-tile 0..127
    const int b   = blockIdx.y;
    const int i0  = it * 32;

    const float* qb = qkv + (size_t)b * DSTACK * N_;
    const float* kb = qb + (size_t)32 * N_;
    const float* vb = qb + (size_t)64 * N_;

    // load q tile: q_s[i][d]
    for (int idx = tid; idx < 32 * 32; idx += 256) {
        const int i = idx >> 5, d = idx & 31;
        q_s[idx] = qb[(size_t)d * N_ + i0 + i];
    }
    if (tid < 32) { m_s[tid] = -INFINITY; l_s[tid] = 0.f; }

    float acc[32];
#pragma unroll
    for (int i = 0; i < 32; ++i) acc[i] = 0.f;
    __syncthreads();

    for (int jc = 0; jc < N_ / 256; ++jc) {
        const int j0 = jc * 256;

        // ---- 1. load k column for j = j0 + tid ----
        float kv[32];
#pragma unroll
        for (int d = 0; d < 32; ++d) kv[d] = kb[(size_t)d * N_ + j0 + tid];

        __syncthreads();   // previous chunk's PV reads of sp are done

        // ---- 2. scores s[i][tid] ----
#pragma unroll 4
        for (int i = 0; i < 32; ++i) {
            const float4* q4 = (const float4*)&q_s[i * 32];
            float s = 0.f;
#pragma unroll
            for (int d4 = 0; d4 < 8; ++d4) {
                const float4 qv = q4[d4];
                s += qv.x * kv[4 * d4 + 0] + qv.y * kv[4 * d4 + 1] +
                     qv.z * kv[4 * d4 + 2] + qv.w * kv[4 * d4 + 3];
            }
            sp[i * SPLD + tid] = s;
        }
        __syncthreads();

        // ---- 3. online softmax update: 8 lanes per i ----
        {
            const int i  = tid >> 3;
            const int l8 = tid & 7;
            float mx = -INFINITY;
#pragma unroll
            for (int t = 0; t < 32; ++t)
                mx = fmaxf(mx, sp[i * SPLD + l8 + 8 * t]);
            mx = fmaxf(mx, __shfl_xor(mx, 1));
            mx = fmaxf(mx, __shfl_xor(mx, 2));
            mx = fmaxf(mx, __shfl_xor(mx, 4));
            const float mold = m_s[i];
            const float mnew = fmaxf(mold, mx);
            float psum = 0.f;
#pragma unroll
            for (int t = 0; t < 32; ++t) {
                const float e = __expf(sp[i * SPLD + l8 + 8 * t] - mnew);
                sp[i * SPLD + l8 + 8 * t] = e;
                psum += e;
            }
            psum += __shfl_xor(psum, 1);
            psum += __shfl_xor(psum, 2);
            psum += __shfl_xor(psum, 4);
            if (l8 == 0) {
                const float al = __expf(mold - mnew);
                l_s[i] = l_s[i] * al + psum;
                m_s[i] = mnew;
                a_s[i] = al;
            }
        }
        __syncthreads();

        // ---- 4. rescale + PV: thread owns channel c = tid ----
#pragma unroll
        for (int i = 0; i < 32; ++i) acc[i] *= a_s[i];

        const float4* v4 = (const float4*)(vb + (size_t)tid * N_ + j0);
        for (int jj = 0; jj < 64; ++jj) {
            const float4 vv = v4[jj];
#pragma unroll
            for (int i = 0; i < 32; ++i) {
                const float4 p = *(const float4*)&sp[i * SPLD + jj * 4];
                acc[i] += p.x * vv.x + p.y * vv.y + p.z * vv.z + p.w * vv.w;
            }
        }
    }
    __syncthreads();   // ensure l_s final (it already is; cheap safety)

    // ---- epilogue: out = alpha * (acc / l) + x ----
    const float av = alpha_p[0];
    const float* xrow = x   + (size_t)b * C_ * N_ + (size_t)tid * N_ + i0;
    float*       orow = out + (size_t)b * C_ * N_ + (size_t)tid * N_ + i0;
#pragma unroll
    for (int i4 = 0; i4 < 8; ++i4) {
        const float4 xi = ((const float4*)xrow)[i4];
        float4 o;
        o.x = av * (acc[4 * i4 + 0] / l_s[4 * i4 + 0]) + xi.x;
        o.y = av * (acc[4 * i4 + 1] / l_s[4 * i4 + 1]) + xi.y;
        o.z = av * (acc[4 * i4 + 2] / l_s[4 * i4 + 2]) + xi.z;
        o.w = av * (acc[4 * i4 + 3] / l_s[4 * i4 + 3]) + xi.w;
        ((float4*)orow)[i4] = o;
    }
}

// ---------------------------------------------------------------------------
extern "C" void kernel_launch(void* const* d_in, const int* in_sizes, int n_in,
                              void* d_out, int out_size, void* d_ws, size_t ws_size,
                              hipStream_t stream)
{
    const float* x  = (const float*)d_in[0];
    const float* wq = (const float*)d_in[1];
    const float* bq = (const float*)d_in[2];
    const float* wk = (const float*)d_in[3];
    const float* bk = (const float*)d_in[4];
    const float* wv = (const float*)d_in[5];
    const float* bv = (const float*)d_in[6];
    const float* al = (const float*)d_in[7];
    float* out = (float*)d_out;
    float* qkv = (float*)d_ws;   // needs B*320*N*4 = 41.9 MB

    proj_kernel<<<dim3(N_ / 256, DSTACK / 32, B_), 256, 0, stream>>>(
        x, wq, bq, wk, bk, wv, bv, qkv);
    attn_kernel<<<dim3(N_ / 32, B_), 256, 0, stream>>>(qkv, x, al, out);
}

// Round 2
// 413.211 us; speedup vs baseline: 4.8456x; 4.8456x over previous
//
#include <hip/hip_runtime.h>
#include <math.h>

// Problem constants (fixed by the reference)
#define B_  8
#define C_  256
#define N_  4096        // H*W
#define CQK 32          // C/8

using frag  = __attribute__((ext_vector_type(8))) short;   // 8 bf16 = 16 B (4 VGPRs)
using f32x4 = __attribute__((ext_vector_type(4))) float;

__device__ __forceinline__ unsigned short f2bf(float f) {   // RNE fp32 -> bf16
    unsigned u = __float_as_uint(f);
    u += 0x7fffu + ((u >> 16) & 1u);
    return (unsigned short)(u >> 16);
}
__device__ __forceinline__ float bf2f(unsigned short h) {
    return __uint_as_float(((unsigned)h) << 16);
}
#define PK2(a, b) (((unsigned)(a)) | (((unsigned)(b)) << 16))

// ---------------------------------------------------------------------------
// Kernel 1: fused qkv projection (fp32 VALU, outputs bf16 for MFMA).
//   qh/ql, kh/kl : [B][N][32]  bf16 (hi/lo split, MFMA frag layout)
//   vbf          : [B][C][N]   bf16
// grid (N/256, 10, B), 256 threads.  dt: 0=q, 1=k, 2..9 = v channel groups.
// ---------------------------------------------------------------------------
__global__ __launch_bounds__(256) void proj_kernel(
    const float* __restrict__ x,
    const float* __restrict__ wq, const float* __restrict__ bq,
    const float* __restrict__ wk, const float* __restrict__ bk,
    const float* __restrict__ wv, const float* __restrict__ bv,
    unsigned short* __restrict__ qh, unsigned short* __restrict__ ql,
    unsigned short* __restrict__ kh, unsigned short* __restrict__ kl,
    unsigned short* __restrict__ vbf)
{
    __shared__ float w_s[32 * 256];
    const int tid = threadIdx.x;
    const int nb  = blockIdx.x;
    const int dt  = blockIdx.y;
    const int b   = blockIdx.z;

    const float* wsrc = (dt == 0) ? wq : (dt == 1) ? wk : wv;
    const int row0 = (dt <= 1) ? 0 : (dt - 2) * 32;

    for (int idx = tid; idx < 32 * 256; idx += 256)
        w_s[idx] = wsrc[row0 * 256 + idx];
    __syncthreads();

    const int n = nb * 256 + tid;
    const float* xp = x + (size_t)b * C_ * N_ + n;

    float acc[32];
#pragma unroll
    for (int d = 0; d < 32; ++d) acc[d] = 0.f;

    for (int c4 = 0; c4 < C_; c4 += 4) {
        const float x0 = xp[(size_t)(c4 + 0) * N_];
        const float x1 = xp[(size_t)(c4 + 1) * N_];
        const float x2 = xp[(size_t)(c4 + 2) * N_];
        const float x3 = xp[(size_t)(c4 + 3) * N_];
#pragma unroll
        for (int d = 0; d < 32; ++d) {
            const float4 w = *(const float4*)&w_s[d * 256 + c4];
            acc[d] += w.x * x0 + w.y * x1 + w.z * x2 + w.w * x3;
        }
    }

    if (dt <= 1) {
        const float* bias = dt ? bk : bq;
        unsigned short hs[32], ls[32];
#pragma unroll
        for (int d = 0; d < 32; ++d) {
            const float f = acc[d] + bias[d];
            hs[d] = f2bf(f);
            ls[d] = f2bf(f - bf2f(hs[d]));
        }
        unsigned short* hdst = (dt ? kh : qh) + ((size_t)b * N_ + n) * 32;
        unsigned short* ldst = (dt ? kl : ql) + ((size_t)b * N_ + n) * 32;
#pragma unroll
        for (int g = 0; g < 4; ++g) {
            uint4 U;
            U.x = PK2(hs[8*g+0], hs[8*g+1]); U.y = PK2(hs[8*g+2], hs[8*g+3]);
            U.z = PK2(hs[8*g+4], hs[8*g+5]); U.w = PK2(hs[8*g+6], hs[8*g+7]);
            ((uint4*)hdst)[g] = U;
            U.x = PK2(ls[8*g+0], ls[8*g+1]); U.y = PK2(ls[8*g+2], ls[8*g+3]);
            U.z = PK2(ls[8*g+4], ls[8*g+5]); U.w = PK2(ls[8*g+6], ls[8*g+7]);
            ((uint4*)ldst)[g] = U;
        }
    } else {
        const int vc0 = (dt - 2) * 32;
#pragma unroll
        for (int d = 0; d < 32; ++d)
            vbf[((size_t)b * C_ + vc0 + d) * N_ + n] = f2bf(acc[d] + bv[vc0 + d]);
    }
}

// ---------------------------------------------------------------------------
// Kernel 2: MFMA flash attention + residual epilogue.
// Block = 256 threads (4 waves) handles (b, 64-row i-tile).
//   wave w: S^T + softmax for i-subtile w (rows i0+16w..+16);
//           PV for channel range [64w, 64w+64) x all 64 i.
// S^T tile via mfma_16x16x32_bf16: D[m=j][n=i] = k_j . q_i  (split-bf16, 3 MFMAs)
// PV: D[m=i][n=c] += P[i][j] * v[c][j]  (A=P from LDS, B=V from global)
// grid (N/64, B).
// ---------------------------------------------------------------------------
__global__ __launch_bounds__(256) void attn_kernel(
    const unsigned short* __restrict__ qh, const unsigned short* __restrict__ ql,
    const unsigned short* __restrict__ khg, const unsigned short* __restrict__ klg,
    const unsigned short* __restrict__ vbf,
    const float* __restrict__ x, const float* __restrict__ alpha_p,
    float* __restrict__ out)
{
    __shared__ __align__(16) short kh_s[64 * 32];
    __shared__ __align__(16) short kl_s[64 * 32];
    __shared__ __align__(16) short p_s[4 * 16 * 72];   // [i-subtile][16 i][72 j] pad
    __shared__ float alpha_s[64];
    __shared__ float l_s[64];

    const int tid  = threadIdx.x;
    const int w    = tid >> 6;        // wave id 0..3
    const int lane = tid & 63;
    const int quad = lane >> 4;
    const int l16  = lane & 15;
    const int b    = blockIdx.y;
    const int i0   = blockIdx.x * 64;

    // Q B-frags (constant over j loop): lane holds q[i = i0+16w+l16][d = 8*quad..+8]
    const size_t qoff = ((size_t)(b * N_ + i0 + w * 16 + l16)) * 32 + quad * 8;
    const frag qhf = *(const frag*)(qh + qoff);
    const frag qlf = *(const frag*)(ql + qoff);

    const unsigned short* khb = khg + (size_t)b * N_ * 32;
    const unsigned short* klb = klg + (size_t)b * N_ * 32;
    const unsigned short* vb  = vbf + (size_t)b * C_ * N_;

    f32x4 o[4][4];                    // [i-tile][c-tile], c = 64w + 16*ct + l16
#pragma unroll
    for (int it = 0; it < 4; ++it)
#pragma unroll
        for (int ct = 0; ct < 4; ++ct)
            o[it][ct] = (f32x4){0.f, 0.f, 0.f, 0.f};

    float m_run = -INFINITY, l_run = 0.f;

    for (int jc = 0; jc < N_ / 64; ++jc) {
        // ---- stage K chunk (64 j x 32 d, hi+lo = 8KB) into LDS ----
        {
            const frag* gh = (const frag*)(khb + (size_t)jc * 64 * 32);
            const frag* gl = (const frag*)(klb + (size_t)jc * 64 * 32);
            ((frag*)kh_s)[tid] = gh[tid];
            ((frag*)kl_s)[tid] = gl[tid];
        }
        __syncthreads();   // barrier A: k_s ready; prev-chunk p_s reads done

        // ---- S^T = K . Q^T for wave's i-subtile, 4 j-subtiles ----
        f32x4 st[4];
#pragma unroll
        for (int js = 0; js < 4; ++js) {
            const frag ka = *(const frag*)&kh_s[(js * 16 + l16) * 32 + quad * 8];
            const frag kb = *(const frag*)&kl_s[(js * 16 + l16) * 32 + quad * 8];
            f32x4 a = (f32x4){0.f, 0.f, 0.f, 0.f};
            a = __builtin_amdgcn_mfma_f32_16x16x32_bf16(ka, qhf, a, 0, 0, 0);
            a = __builtin_amdgcn_mfma_f32_16x16x32_bf16(ka, qlf, a, 0, 0, 0);
            a = __builtin_amdgcn_mfma_f32_16x16x32_bf16(kb, qhf, a, 0, 0, 0);
            st[js] = a;
        }

        // ---- online softmax for the chunk (rows i = l16, j over regs+quads) ----
        float mx = -INFINITY;
#pragma unroll
        for (int js = 0; js < 4; ++js)
#pragma unroll
            for (int r = 0; r < 4; ++r) mx = fmaxf(mx, st[js][r]);
        mx = fmaxf(mx, __shfl_xor(mx, 16));
        mx = fmaxf(mx, __shfl_xor(mx, 32));
        const float mnew = fmaxf(m_run, mx);
        const float sc   = __expf(m_run - mnew);
        float ps = 0.f;
#pragma unroll
        for (int js = 0; js < 4; ++js)
#pragma unroll
            for (int r = 0; r < 4; ++r) {
                const float e = __expf(st[js][r] - mnew);
                st[js][r] = e;
                ps += e;
            }
        ps += __shfl_xor(ps, 16);
        ps += __shfl_xor(ps, 32);
        l_run = l_run * sc + ps;
        m_run = mnew;
        if (quad == 0) alpha_s[w * 16 + l16] = sc;

        // ---- P -> bf16 -> LDS (A-frag layout for PV) ----
#pragma unroll
        for (int js = 0; js < 4; ++js) {
            const unsigned p01 = PK2(f2bf(st[js][0]), f2bf(st[js][1]));
            const unsigned p23 = PK2(f2bf(st[js][2]), f2bf(st[js][3]));
            *(uint2*)&p_s[(w * 16 + l16) * 72 + js * 16 + quad * 4] = make_uint2(p01, p23);
        }
        __syncthreads();   // barrier B: p_s + alpha_s ready

        // ---- rescale O by alpha (per-i factors from LDS, broadcast reads) ----
#pragma unroll
        for (int it = 0; it < 4; ++it)
#pragma unroll
            for (int r = 0; r < 4; ++r) {
                const float a = alpha_s[it * 16 + quad * 4 + r];
#pragma unroll
                for (int ct = 0; ct < 4; ++ct) o[it][ct][r] *= a;
            }

        // ---- PV: K=32 steps, A = P (LDS), B = V (global, L2-resident) ----
#pragma unroll
        for (int ks = 0; ks < 2; ++ks) {
            frag vf[4];
#pragma unroll
            for (int ct = 0; ct < 4; ++ct)
                vf[ct] = *(const frag*)(vb + (size_t)(w * 64 + ct * 16 + l16) * N_
                                        + jc * 64 + ks * 32 + quad * 8);
#pragma unroll
            for (int it = 0; it < 4; ++it) {
                const frag pf = *(const frag*)&p_s[(it * 16 + l16) * 72 + ks * 32 + quad * 8];
#pragma unroll
                for (int ct = 0; ct < 4; ++ct)
                    o[it][ct] = __builtin_amdgcn_mfma_f32_16x16x32_bf16(pf, vf[ct], o[it][ct], 0, 0, 0);
            }
        }
        // next chunk's barrier A protects p_s (PV reads) vs next softmax writes
    }

    // ---- epilogue: out = alpha * O / l + x ----
    if (quad == 0) l_s[w * 16 + l16] = l_run;
    __syncthreads();
    const float av = alpha_p[0];

#pragma unroll
    for (int it = 0; it < 4; ++it) {
        float invl[4];
#pragma unroll
        for (int r = 0; r < 4; ++r) invl[r] = 1.f / l_s[it * 16 + quad * 4 + r];
#pragma unroll
        for (int ct = 0; ct < 4; ++ct) {
            const int c = w * 64 + ct * 16 + l16;
            const size_t base = (size_t)b * C_ * N_ + (size_t)c * N_ + i0 + it * 16 + quad * 4;
            const float4 xv = *(const float4*)(x + base);
            float4 ov;
            ov.x = av * (o[it][ct][0] * invl[0]) + xv.x;
            ov.y = av * (o[it][ct][1] * invl[1]) + xv.y;
            ov.z = av * (o[it][ct][2] * invl[2]) + xv.z;
            ov.w = av * (o[it][ct][3] * invl[3]) + xv.w;
            *(float4*)(out + base) = ov;
        }
    }
}

// ---------------------------------------------------------------------------
extern "C" void kernel_launch(void* const* d_in, const int* in_sizes, int n_in,
                              void* d_out, int out_size, void* d_ws, size_t ws_size,
                              hipStream_t stream)
{
    const float* x  = (const float*)d_in[0];
    const float* wq = (const float*)d_in[1];
    const float* bq = (const float*)d_in[2];
    const float* wk = (const float*)d_in[3];
    const float* bk = (const float*)d_in[4];
    const float* wv = (const float*)d_in[5];
    const float* bv = (const float*)d_in[6];
    const float* al = (const float*)d_in[7];
    float* out = (float*)d_out;

    // workspace layout (bf16 = unsigned short):
    //   qh, ql, kh, kl: 2 MB each ([B][N][32]); vbf: 16 MB ([B][C][N])  => 24 MB
    char* ws = (char*)d_ws;
    unsigned short* qh  = (unsigned short*)(ws + 0);
    unsigned short* ql  = (unsigned short*)(ws + (size_t)2  * 1024 * 1024);
    unsigned short* kh  = (unsigned short*)(ws + (size_t)4  * 1024 * 1024);
    unsigned short* kl  = (unsigned short*)(ws + (size_t)6  * 1024 * 1024);
    unsigned short* vbf = (unsigned short*)(ws + (size_t)8  * 1024 * 1024);

    proj_kernel<<<dim3(N_ / 256, 10, B_), 256, 0, stream>>>(
        x, wq, bq, wk, bk, wv, bv, qh, ql, kh, kl, vbf);
    attn_kernel<<<dim3(N_ / 64, B_), 256, 0, stream>>>(
        qh, ql, kh, kl, vbf, x, al, out);
}

// Round 3
// 307.865 us; speedup vs baseline: 6.5037x; 1.3422x over previous
//
#include <hip/hip_runtime.h>
#include <math.h>

// Problem constants (fixed by the reference)
#define B_  8
#define C_  256
#define N_  4096        // H*W
#define CQK 32          // C/8

using frag  = __attribute__((ext_vector_type(8))) short;   // 8 bf16 = 16 B (4 VGPRs)
using f32x4 = __attribute__((ext_vector_type(4))) float;

__device__ __forceinline__ unsigned short f2bf(float f) {   // RNE fp32 -> bf16
    unsigned u = __float_as_uint(f);
    u += 0x7fffu + ((u >> 16) & 1u);
    return (unsigned short)(u >> 16);
}
__device__ __forceinline__ float bf2f(unsigned short h) {
    return __uint_as_float(((unsigned)h) << 16);
}
#define PK2(a, b) (((unsigned)(a)) | (((unsigned)(b)) << 16))

// ---------------------------------------------------------------------------
// Kernel 1: MFMA qkv projection.
// Block = 256 threads (4 waves), handles (n-tile of 128 pixels) x (32 out-ch).
// grid (N/128, 10, B).  dt: 0=q, 1=k, 2..9 = v channel groups of 32.
// D[m = out-ch][n = pixel] = sum_c W[m][c] * x[c][n]  via mfma_16x16x32_bf16.
//   A = W from frag-ordered LDS (conflict-free b128), hi/lo split for q/k.
//   B = X direct from global fp32 (stride-N gather, L2-resident), converted
//       in-register to bf16 hi(/lo).
// Outputs (same layouts attn_kernel consumed in R1):
//   qh/ql, kh/kl : [B][N][32] bf16 hi/lo;  vbf : [B][C][N] bf16.
// ---------------------------------------------------------------------------
__global__ __launch_bounds__(256) void proj_kernel(
    const float* __restrict__ x,
    const float* __restrict__ wq, const float* __restrict__ bq,
    const float* __restrict__ wk, const float* __restrict__ bk,
    const float* __restrict__ wv, const float* __restrict__ bv,
    unsigned short* __restrict__ qh, unsigned short* __restrict__ ql,
    unsigned short* __restrict__ kh, unsigned short* __restrict__ kl,
    unsigned short* __restrict__ vbf)
{
    // frag-ordered weights: frag f -> (kc = f>>7, m = (f>>6)&1, lane = f&63)
    // lane reads 16 B at whf + f*16  -> conflict-free ds_read_b128
    __shared__ __align__(16) unsigned short whf[1024 * 8];   // 16 KB
    __shared__ __align__(16) unsigned short wlf[1024 * 8];   // 16 KB (qk only)

    const int tid  = threadIdx.x;
    const int w    = tid >> 6;
    const int lane = tid & 63;
    const int quad = lane >> 4;
    const int l16  = lane & 15;
    const int n0   = blockIdx.x * 128;
    const int dt   = blockIdx.y;
    const int b    = blockIdx.z;
    const bool is_qk = (dt <= 1);

    const float* wsrc = (dt == 0) ? wq : (dt == 1) ? wk : wv;
    const int row0 = is_qk ? 0 : (dt - 2) * 32;

    // ---- stage W [32][256] into frag-ordered LDS (each thread: 4 frags) ----
#pragma unroll
    for (int it = 0; it < 4; ++it) {
        const int f   = it * 256 + tid;
        const int fl  = f & 63;
        const int m   = (f >> 6) & 1;
        const int kc  = f >> 7;
        const int row = m * 16 + (fl & 15);
        const int c0  = kc * 32 + ((fl >> 4) & 3) * 8;
        const float* wp = wsrc + (row0 + row) * 256 + c0;
        const float4 a = *(const float4*)wp;
        const float4 c = *(const float4*)(wp + 4);
        unsigned short h[8];
        h[0]=f2bf(a.x); h[1]=f2bf(a.y); h[2]=f2bf(a.z); h[3]=f2bf(a.w);
        h[4]=f2bf(c.x); h[5]=f2bf(c.y); h[6]=f2bf(c.z); h[7]=f2bf(c.w);
        uint4 U; U.x=PK2(h[0],h[1]); U.y=PK2(h[2],h[3]); U.z=PK2(h[4],h[5]); U.w=PK2(h[6],h[7]);
        *(uint4*)&whf[f * 8] = U;
        if (is_qk) {
            unsigned short g[8];
            g[0]=f2bf(a.x-bf2f(h[0])); g[1]=f2bf(a.y-bf2f(h[1]));
            g[2]=f2bf(a.z-bf2f(h[2])); g[3]=f2bf(a.w-bf2f(h[3]));
            g[4]=f2bf(c.x-bf2f(h[4])); g[5]=f2bf(c.y-bf2f(h[5]));
            g[6]=f2bf(c.z-bf2f(h[6])); g[7]=f2bf(c.w-bf2f(h[7]));
            uint4 V; V.x=PK2(g[0],g[1]); V.y=PK2(g[2],g[3]); V.z=PK2(g[4],g[5]); V.w=PK2(g[6],g[7]);
            *(uint4*)&wlf[f * 8] = V;
        }
    }
    __syncthreads();

    f32x4 acc[2][2];   // [m-subtile][n-subtile], wave w owns pixels n0+32w..+32
#pragma unroll
    for (int m = 0; m < 2; ++m)
#pragma unroll
        for (int nr = 0; nr < 2; ++nr)
            acc[m][nr] = (f32x4){0.f, 0.f, 0.f, 0.f};

    for (int kc = 0; kc < 8; ++kc) {
        frag ah[2], al[2];
        ah[0] = ((const frag*)whf)[kc * 128 + 0 * 64 + lane];
        ah[1] = ((const frag*)whf)[kc * 128 + 1 * 64 + lane];
        if (is_qk) {
            al[0] = ((const frag*)wlf)[kc * 128 + 0 * 64 + lane];
            al[1] = ((const frag*)wlf)[kc * 128 + 1 * 64 + lane];
        }

#pragma unroll
        for (int nr = 0; nr < 2; ++nr) {
            const int n = n0 + (w * 2 + nr) * 16 + l16;
            const float* xp = x + (size_t)b * C_ * N_
                              + (size_t)(kc * 32 + quad * 8) * N_ + n;
            float xv[8];
#pragma unroll
            for (int j = 0; j < 8; ++j) xv[j] = xp[(size_t)j * N_];

            frag bh;
#pragma unroll
            for (int j = 0; j < 8; ++j) bh[j] = (short)f2bf(xv[j]);

            if (is_qk) {
                frag bl;
#pragma unroll
                for (int j = 0; j < 8; ++j)
                    bl[j] = (short)f2bf(xv[j] - bf2f((unsigned short)bh[j]));
#pragma unroll
                for (int m = 0; m < 2; ++m) {
                    acc[m][nr] = __builtin_amdgcn_mfma_f32_16x16x32_bf16(ah[m], bh, acc[m][nr], 0, 0, 0);
                    acc[m][nr] = __builtin_amdgcn_mfma_f32_16x16x32_bf16(al[m], bh, acc[m][nr], 0, 0, 0);
                    acc[m][nr] = __builtin_amdgcn_mfma_f32_16x16x32_bf16(ah[m], bl, acc[m][nr], 0, 0, 0);
                }
            } else {
#pragma unroll
                for (int m = 0; m < 2; ++m)
                    acc[m][nr] = __builtin_amdgcn_mfma_f32_16x16x32_bf16(ah[m], bh, acc[m][nr], 0, 0, 0);
            }
        }
    }

    // ---- epilogue: bias add, store.  D row = quad*4+r, col = l16 ----
    if (is_qk) {
        const float* bias = dt ? bk : bq;
        unsigned short* hdst = dt ? kh : qh;
        unsigned short* ldst = dt ? kl : ql;
#pragma unroll
        for (int m = 0; m < 2; ++m)
#pragma unroll
            for (int nr = 0; nr < 2; ++nr) {
                const int n = n0 + (w * 2 + nr) * 16 + l16;
                const int dbase = m * 16 + quad * 4;
                unsigned short hs[4], ls[4];
#pragma unroll
                for (int r = 0; r < 4; ++r) {
                    const float f = acc[m][nr][r] + bias[dbase + r];
                    hs[r] = f2bf(f);
                    ls[r] = f2bf(f - bf2f(hs[r]));
                }
                const size_t off = ((size_t)(b * N_ + n)) * 32 + dbase;
                *(uint2*)&hdst[off] = make_uint2(PK2(hs[0], hs[1]), PK2(hs[2], hs[3]));
                *(uint2*)&ldst[off] = make_uint2(PK2(ls[0], ls[1]), PK2(ls[2], ls[3]));
            }
    } else {
        const int vc0 = (dt - 2) * 32;
#pragma unroll
        for (int m = 0; m < 2; ++m)
#pragma unroll
            for (int nr = 0; nr < 2; ++nr) {
                const int n = n0 + (w * 2 + nr) * 16 + l16;
#pragma unroll
                for (int r = 0; r < 4; ++r) {
                    const int cch = vc0 + m * 16 + quad * 4 + r;
                    vbf[((size_t)b * C_ + cch) * N_ + n] = f2bf(acc[m][nr][r] + bv[cch]);
                }
            }
    }
}

// ---------------------------------------------------------------------------
// Kernel 2: MFMA flash attention + residual epilogue (unchanged from R1).
// grid (N/64, B), 256 threads (4 waves).
// ---------------------------------------------------------------------------
__global__ __launch_bounds__(256) void attn_kernel(
    const unsigned short* __restrict__ qh, const unsigned short* __restrict__ ql,
    const unsigned short* __restrict__ khg, const unsigned short* __restrict__ klg,
    const unsigned short* __restrict__ vbf,
    const float* __restrict__ x, const float* __restrict__ alpha_p,
    float* __restrict__ out)
{
    __shared__ __align__(16) short kh_s[64 * 32];
    __shared__ __align__(16) short kl_s[64 * 32];
    __shared__ __align__(16) short p_s[4 * 16 * 72];   // [i-subtile][16 i][72 j] pad
    __shared__ float alpha_s[64];
    __shared__ float l_s[64];

    const int tid  = threadIdx.x;
    const int w    = tid >> 6;        // wave id 0..3
    const int lane = tid & 63;
    const int quad = lane >> 4;
    const int l16  = lane & 15;
    const int b    = blockIdx.y;
    const int i0   = blockIdx.x * 64;

    const size_t qoff = ((size_t)(b * N_ + i0 + w * 16 + l16)) * 32 + quad * 8;
    const frag qhf = *(const frag*)(qh + qoff);
    const frag qlf = *(const frag*)(ql + qoff);

    const unsigned short* khb = khg + (size_t)b * N_ * 32;
    const unsigned short* klb = klg + (size_t)b * N_ * 32;
    const unsigned short* vb  = vbf + (size_t)b * C_ * N_;

    f32x4 o[4][4];                    // [i-tile][c-tile], c = 64w + 16*ct + l16
#pragma unroll
    for (int it = 0; it < 4; ++it)
#pragma unroll
        for (int ct = 0; ct < 4; ++ct)
            o[it][ct] = (f32x4){0.f, 0.f, 0.f, 0.f};

    float m_run = -INFINITY, l_run = 0.f;

    for (int jc = 0; jc < N_ / 64; ++jc) {
        {
            const frag* gh = (const frag*)(khb + (size_t)jc * 64 * 32);
            const frag* gl = (const frag*)(klb + (size_t)jc * 64 * 32);
            ((frag*)kh_s)[tid] = gh[tid];
            ((frag*)kl_s)[tid] = gl[tid];
        }
        __syncthreads();   // barrier A: k_s ready; prev-chunk p_s reads done

        f32x4 st[4];
#pragma unroll
        for (int js = 0; js < 4; ++js) {
            const frag ka = *(const frag*)&kh_s[(js * 16 + l16) * 32 + quad * 8];
            const frag kb = *(const frag*)&kl_s[(js * 16 + l16) * 32 + quad * 8];
            f32x4 a = (f32x4){0.f, 0.f, 0.f, 0.f};
            a = __builtin_amdgcn_mfma_f32_16x16x32_bf16(ka, qhf, a, 0, 0, 0);
            a = __builtin_amdgcn_mfma_f32_16x16x32_bf16(ka, qlf, a, 0, 0, 0);
            a = __builtin_amdgcn_mfma_f32_16x16x32_bf16(kb, qhf, a, 0, 0, 0);
            st[js] = a;
        }

        float mx = -INFINITY;
#pragma unroll
        for (int js = 0; js < 4; ++js)
#pragma unroll
            for (int r = 0; r < 4; ++r) mx = fmaxf(mx, st[js][r]);
        mx = fmaxf(mx, __shfl_xor(mx, 16));
        mx = fmaxf(mx, __shfl_xor(mx, 32));
        const float mnew = fmaxf(m_run, mx);
        const float sc   = __expf(m_run - mnew);
        float ps = 0.f;
#pragma unroll
        for (int js = 0; js < 4; ++js)
#pragma unroll
            for (int r = 0; r < 4; ++r) {
                const float e = __expf(st[js][r] - mnew);
                st[js][r] = e;
                ps += e;
            }
        ps += __shfl_xor(ps, 16);
        ps += __shfl_xor(ps, 32);
        l_run = l_run * sc + ps;
        m_run = mnew;
        if (quad == 0) alpha_s[w * 16 + l16] = sc;

#pragma unroll
        for (int js = 0; js < 4; ++js) {
            const unsigned p01 = PK2(f2bf(st[js][0]), f2bf(st[js][1]));
            const unsigned p23 = PK2(f2bf(st[js][2]), f2bf(st[js][3]));
            *(uint2*)&p_s[(w * 16 + l16) * 72 + js * 16 + quad * 4] = make_uint2(p01, p23);
        }
        __syncthreads();   // barrier B: p_s + alpha_s ready

#pragma unroll
        for (int it = 0; it < 4; ++it)
#pragma unroll
            for (int r = 0; r < 4; ++r) {
                const float a = alpha_s[it * 16 + quad * 4 + r];
#pragma unroll
                for (int ct = 0; ct < 4; ++ct) o[it][ct][r] *= a;
            }

#pragma unroll
        for (int ks = 0; ks < 2; ++ks) {
            frag vf[4];
#pragma unroll
            for (int ct = 0; ct < 4; ++ct)
                vf[ct] = *(const frag*)(vb + (size_t)(w * 64 + ct * 16 + l16) * N_
                                        + jc * 64 + ks * 32 + quad * 8);
#pragma unroll
            for (int it = 0; it < 4; ++it) {
                const frag pf = *(const frag*)&p_s[(it * 16 + l16) * 72 + ks * 32 + quad * 8];
#pragma unroll
                for (int ct = 0; ct < 4; ++ct)
                    o[it][ct] = __builtin_amdgcn_mfma_f32_16x16x32_bf16(pf, vf[ct], o[it][ct], 0, 0, 0);
            }
        }
    }

    if (quad == 0) l_s[w * 16 + l16] = l_run;
    __syncthreads();
    const float av = alpha_p[0];

#pragma unroll
    for (int it = 0; it < 4; ++it) {
        float invl[4];
#pragma unroll
        for (int r = 0; r < 4; ++r) invl[r] = 1.f / l_s[it * 16 + quad * 4 + r];
#pragma unroll
        for (int ct = 0; ct < 4; ++ct) {
            const int c = w * 64 + ct * 16 + l16;
            const size_t base = (size_t)b * C_ * N_ + (size_t)c * N_ + i0 + it * 16 + quad * 4;
            const float4 xv = *(const float4*)(x + base);
            float4 ov;
            ov.x = av * (o[it][ct][0] * invl[0]) + xv.x;
            ov.y = av * (o[it][ct][1] * invl[1]) + xv.y;
            ov.z = av * (o[it][ct][2] * invl[2]) + xv.z;
            ov.w = av * (o[it][ct][3] * invl[3]) + xv.w;
            *(float4*)(out + base) = ov;
        }
    }
}

// ---------------------------------------------------------------------------
extern "C" void kernel_launch(void* const* d_in, const int* in_sizes, int n_in,
                              void* d_out, int out_size, void* d_ws, size_t ws_size,
                              hipStream_t stream)
{
    const float* x  = (const float*)d_in[0];
    const float* wq = (const float*)d_in[1];
    const float* bq = (const float*)d_in[2];
    const float* wk = (const float*)d_in[3];
    const float* bk = (const float*)d_in[4];
    const float* wv = (const float*)d_in[5];
    const float* bv = (const float*)d_in[6];
    const float* al = (const float*)d_in[7];
    float* out = (float*)d_out;

    // workspace: qh, ql, kh, kl: 2 MB each ([B][N][32]); vbf: 16 MB ([B][C][N])
    char* ws = (char*)d_ws;
    unsigned short* qh  = (unsigned short*)(ws + 0);
    unsigned short* ql  = (unsigned short*)(ws + (size_t)2  * 1024 * 1024);
    unsigned short* kh  = (unsigned short*)(ws + (size_t)4  * 1024 * 1024);
    unsigned short* kl  = (unsigned short*)(ws + (size_t)6  * 1024 * 1024);
    unsigned short* vbf = (unsigned short*)(ws + (size_t)8  * 1024 * 1024);

    proj_kernel<<<dim3(N_ / 128, 10, B_), 256, 0, stream>>>(
        x, wq, bq, wk, bk, wv, bv, qh, ql, kh, kl, vbf);
    attn_kernel<<<dim3(N_ / 64, B_), 256, 0, stream>>>(
        qh, ql, kh, kl, vbf, x, al, out);
}